// Round 1
// baseline (12860.828 us; speedup 1.0000x reference)
//
#include <hip/hip_runtime.h>

typedef __attribute__((ext_vector_type(8))) short short8;
typedef __attribute__((ext_vector_type(4))) float f32x4;

#define TT 512
#define HD 1024
#define BD 64
#define NWG 256

// ---- fp32 -> bf16 round-to-nearest-even (bit twiddle; avoids hip_bf16 API) ----
__device__ __forceinline__ unsigned short f2bf(float f) {
  unsigned u = __float_as_uint(f);
  u += 0x7fffu + ((u >> 16) & 1u);
  return (unsigned short)(u >> 16);
}

// ============================================================================
// Prep: convert inputs [B][T][512] fp32 -> XT bf16 in MFMA A-fragment order:
//   XT unit index = ((bt*T + t)*16 + ks)*64 + q*16 + m ; element j
//   holds x[b=bt*16+m][t][k=ks*32+q*8+j]
// so the scan's A-fragment loads are lane-contiguous 16B (perfectly coalesced).
// ============================================================================
__global__ void prep_xt(const float* __restrict__ x, short8* __restrict__ XT) {
  const int bid = blockIdx.x;        // 0..32767 = b*512 + t
  const int b = bid >> 9;
  const int t = bid & 511;
  const int tid = threadIdx.x;       // 0..63 : k-octet
  const float* src = x + ((size_t)(b * TT + t)) * 512 + tid * 8;
  const f32x4* s4 = (const f32x4*)src;
  f32x4 lo = s4[0], hi = s4[1];
  short8 o;
#pragma unroll
  for (int j = 0; j < 4; ++j) {
    o[j] = (short)f2bf(lo[j]);
    o[4 + j] = (short)f2bf(hi[j]);
  }
  const int bt = b >> 4, m = b & 15, ks = tid >> 2, q = tid & 3;
  XT[(((size_t)bt * TT + t) * 16 + ks) * 64 + q * 16 + m] = o;
}

// ============================================================================
// Device-scope grid barrier (256 WGs, 1 per CU, all co-resident by LDS sizing).
// bar[0] = arrival counter, bar[1] = generation.
// __threadfence() before arrival publishes this WG's h-writes (L2 writeback to
// LLC); after release, acquire side invalidates stale per-XCD L2 lines (G16).
// ============================================================================
__device__ __forceinline__ void grid_barrier(unsigned* bar) {
  __syncthreads();  // drains vmcnt(0): all WG stores at least in L2
  if (threadIdx.x == 0) {
    __threadfence();
    unsigned g = __hip_atomic_load(bar + 1, __ATOMIC_RELAXED, __HIP_MEMORY_SCOPE_AGENT);
    unsigned old = __hip_atomic_fetch_add(bar, 1u, __ATOMIC_RELAXED, __HIP_MEMORY_SCOPE_AGENT);
    if (old == NWG - 1) {
      __hip_atomic_store(bar, 0u, __ATOMIC_RELAXED, __HIP_MEMORY_SCOPE_AGENT);
      __hip_atomic_store(bar + 1, g + 1u, __ATOMIC_RELEASE, __HIP_MEMORY_SCOPE_AGENT);
    } else {
      while (__hip_atomic_load(bar + 1, __ATOMIC_RELAXED, __HIP_MEMORY_SCOPE_AGENT) == g) {
        __builtin_amdgcn_s_sleep(1);
      }
    }
    __threadfence();
  }
  __syncthreads();
}

// ============================================================================
// Persistent fused GRU scan. 256 WGs = (bt in 0..3) x (ct in 0..63).
// WG owns output tile [16 batches x 16 cols]; all weights for its 16 cols
// (Whr/Whz/Whn K=1024 and Wxr/Wxz/Wxn K=512) live in LDS in B-fragment order.
// K is split across the 4 waves; partials reduced through LDS.
// LDS: wh 96KB + wx 48KB + red 8KB = 152KB -> exactly 1 WG/CU.
// ============================================================================
__global__ __launch_bounds__(256, 1) void gru_main(
    const float* __restrict__ Wxr, const float* __restrict__ bxr,
    const float* __restrict__ Whr,
    const float* __restrict__ Wxz, const float* __restrict__ bxz,
    const float* __restrict__ Whz,
    const float* __restrict__ Wxn, const float* __restrict__ bxn,
    const float* __restrict__ Whn,
    const short8* __restrict__ XT, short* __restrict__ HF,
    unsigned* __restrict__ bar, float* __restrict__ out) {
  extern __shared__ char lds[];
  short8* wh = (short8*)lds;               // [3][32][64] units of 8 bf16
  short8* wx = (short8*)(lds + 98304);     // [3][16][64]
  float* red = (float*)(lds + 147456);     // [2][4][64][4] fp32

  const int wg = blockIdx.x;
  const int bt = wg >> 6;
  const int ct = wg & 63;
  const int c0 = ct << 4;
  const int tid = threadIdx.x;
  const int wv = tid >> 6;
  const int lane = tid & 63;

  // ---- stage Wh into LDS, fragment-major: lane holds W[c0+(lane&15)][ks*32+(lane>>4)*8+j]
  for (int idx = tid; idx < 3 * 32 * 64; idx += 256) {
    const int g = idx >> 11, rem = idx & 2047, ks = rem >> 6, ln = rem & 63;
    const float* W = (g == 0) ? Whr : (g == 1) ? Whz : Whn;
    const float* src = W + (size_t)(c0 + (ln & 15)) * HD + ks * 32 + (ln >> 4) * 8;
    short8 v;
#pragma unroll
    for (int j = 0; j < 8; ++j) v[j] = (short)f2bf(src[j]);
    wh[idx] = v;
  }
  // ---- stage Wx (K=512) likewise
  for (int idx = tid; idx < 3 * 16 * 64; idx += 256) {
    const int g = idx >> 10, rem = idx & 1023, ks = rem >> 6, ln = rem & 63;
    const float* W = (g == 0) ? Wxr : (g == 1) ? Wxz : Wxn;
    const float* src = W + (size_t)(c0 + (ln & 15)) * 512 + ks * 32 + (ln >> 4) * 8;
    short8 v;
#pragma unroll
    for (int j = 0; j < 8; ++j) v[j] = (short)f2bf(src[j]);
    wx[idx] = v;
  }

  // ---- per-thread output element ownership (fixed for all t)
  const int c_off = tid & 15, b_off = tid >> 4;
  const int c = c0 + c_off;
  const int b = (bt << 4) + b_off;
  const float br_ = bxr[c], bz_ = bxz[c], bn_ = bxn[c];
  float h_old = 0.f;

  // HF element slot for (b,c) in fragment layout (per parity: 65536 bf16)
  const int hf_elem = (((bt * 32 + (c >> 5)) * 64) + ((c >> 3) & 3) * 16 + b_off) * 8 + (c & 7);
  HF[hf_elem] = 0;  // h0 = 0 in parity-0 buffer

  float* out_hlast = out;
  float* out_hidden = out + BD * HD;

  grid_barrier(bar);  // h0 zeros visible everywhere

  const short8* hf8 = (const short8*)HF;
  const int rl = ((b_off >> 2) << 4) + c_off;  // producer lane for (b_off,c_off)
  const int rr = b_off & 3;                    // producer register

  for (int t = 0; t < TT; ++t) {
    const int p = t & 1;
    f32x4 aR = {0.f, 0.f, 0.f, 0.f};
    f32x4 aZ = {0.f, 0.f, 0.f, 0.f};
    f32x4 aNh = {0.f, 0.f, 0.f, 0.f};
    f32x4 aNx = {0.f, 0.f, 0.f, 0.f};

    // ---- recurrent part: wave wv covers ksteps wv*8 .. wv*8+7 (K=1024)
    const short8* hrd = hf8 + p * 8192 + (bt * 32 + (wv << 3)) * 64 + lane;
#pragma unroll
    for (int kk = 0; kk < 8; ++kk) {
      const int ks = (wv << 3) + kk;
      short8 a = hrd[kk * 64];
      aR = __builtin_amdgcn_mfma_f32_16x16x32_bf16(a, wh[(0 * 32 + ks) * 64 + lane], aR, 0, 0, 0);
      aZ = __builtin_amdgcn_mfma_f32_16x16x32_bf16(a, wh[(1 * 32 + ks) * 64 + lane], aZ, 0, 0, 0);
      aNh = __builtin_amdgcn_mfma_f32_16x16x32_bf16(a, wh[(2 * 32 + ks) * 64 + lane], aNh, 0, 0, 0);
    }
    // ---- input part: wave wv covers ksteps wv*4 .. wv*4+3 (K=512)
    const short8* xrd = XT + (((size_t)bt * TT + t) * 16 + (wv << 2)) * 64 + lane;
#pragma unroll
    for (int kk = 0; kk < 4; ++kk) {
      const int ks = (wv << 2) + kk;
      short8 a = xrd[kk * 64];
      aR = __builtin_amdgcn_mfma_f32_16x16x32_bf16(a, wx[(0 * 16 + ks) * 64 + lane], aR, 0, 0, 0);
      aZ = __builtin_amdgcn_mfma_f32_16x16x32_bf16(a, wx[(1 * 16 + ks) * 64 + lane], aZ, 0, 0, 0);
      aNx = __builtin_amdgcn_mfma_f32_16x16x32_bf16(a, wx[(2 * 16 + ks) * 64 + lane], aNx, 0, 0, 0);
    }

    // ---- cross-wave K-reduction, round 1: R and Z
    {
      f32x4* r4 = (f32x4*)red;
      r4[(0 * 4 + wv) * 64 + lane] = aR;
      r4[(1 * 4 + wv) * 64 + lane] = aZ;
    }
    __syncthreads();
    float sR = 0.f, sZ = 0.f;
#pragma unroll
    for (int v = 0; v < 4; ++v) {
      sR += red[((0 * 4 + v) * 64 + rl) * 4 + rr];
      sZ += red[((1 * 4 + v) * 64 + rl) * 4 + rr];
    }
    __syncthreads();
    // ---- round 2: Nh (h-matmul, gets multiplied by r) and Nx (x part)
    {
      f32x4* r4 = (f32x4*)red;
      r4[(0 * 4 + wv) * 64 + lane] = aNh;
      r4[(1 * 4 + wv) * 64 + lane] = aNx;
    }
    __syncthreads();
    float sNh = 0.f, sNx = 0.f;
#pragma unroll
    for (int v = 0; v < 4; ++v) {
      sNh += red[((0 * 4 + v) * 64 + rl) * 4 + rr];
      sNx += red[((1 * 4 + v) * 64 + rl) * 4 + rr];
    }

    // ---- gates (fp32 exact recurrence state in register)
    const float r = 1.f / (1.f + __expf(-(sR + br_)));
    const float z = 1.f / (1.f + __expf(-(sZ + bz_)));
    float pre_n = sNx + bn_ + r * sNh;
    pre_n = fminf(fmaxf(pre_n, -30.f), 30.f);
    const float e2 = __expf(2.f * pre_n);
    const float n = (e2 - 1.f) / (e2 + 1.f);
    const float hn = (1.f - z) * n + z * h_old;
    h_old = hn;

    out_hidden[((size_t)b * TT + t) * HD + c] = hn;
    if (t == TT - 1) out_hlast[(size_t)b * HD + c] = hn;
    HF[(1 - p) * 65536 + hf_elem] = (short)f2bf(hn);

    grid_barrier(bar);
  }
}

// ============================================================================
extern "C" void kernel_launch(void* const* d_in, const int* in_sizes, int n_in,
                              void* d_out, int out_size, void* d_ws, size_t ws_size,
                              hipStream_t stream) {
  const float* inputs = (const float*)d_in[0];
  const float* Wxr = (const float*)d_in[1];
  const float* bxr = (const float*)d_in[2];
  const float* Whr = (const float*)d_in[3];
  const float* Wxz = (const float*)d_in[4];
  const float* bxz = (const float*)d_in[5];
  const float* Whz = (const float*)d_in[6];
  const float* Wxn = (const float*)d_in[7];
  const float* bxn = (const float*)d_in[8];
  const float* Whn = (const float*)d_in[9];
  float* out = (float*)d_out;

  char* ws = (char*)d_ws;
  short8* XT = (short8*)ws;                              // 33,554,432 B
  short* HF = (short*)(ws + 33554432);                   //    262,144 B
  unsigned* bar = (unsigned*)(ws + 33554432 + 262144);   //         16 B

  hipMemsetAsync(bar, 0, 16, stream);
  prep_xt<<<dim3(64 * 512), dim3(64), 0, stream>>>(inputs, XT);

  (void)hipFuncSetAttribute((const void*)gru_main,
                            hipFuncAttributeMaxDynamicSharedMemorySize, 155648);
  gru_main<<<dim3(NWG), dim3(256), 155648, stream>>>(
      Wxr, bxr, Whr, Wxz, bxz, Whz, Wxn, bxn, Whn, XT, HF, bar, out);
}

// Round 2
// 2166.110 us; speedup vs baseline: 5.9373x; 5.9373x over previous
//
#include <hip/hip_runtime.h>

typedef __attribute__((ext_vector_type(8))) short short8;
typedef __attribute__((ext_vector_type(4))) float f32x4;

#define TT 512
#define HD 1024
#define BD 64
#define NWG 256

union U16B { short8 s; unsigned long long u[2]; };

// ---- fp32 -> bf16 round-to-nearest-even ----
__device__ __forceinline__ unsigned short f2bf(float f) {
  unsigned u = __float_as_uint(f);
  u += 0x7fffu + ((u >> 16) & 1u);
  return (unsigned short)(u >> 16);
}

// ============================================================================
// Prep: inputs [B][T][512] fp32 -> XT bf16 in MFMA A-fragment order.
// ============================================================================
__global__ void prep_xt(const float* __restrict__ x, short8* __restrict__ XT) {
  const int bid = blockIdx.x;  // b*512 + t
  const int b = bid >> 9;
  const int t = bid & 511;
  const int tid = threadIdx.x;  // k-octet
  const float* src = x + ((size_t)(b * TT + t)) * 512 + tid * 8;
  const f32x4* s4 = (const f32x4*)src;
  f32x4 lo = s4[0], hi = s4[1];
  short8 o;
#pragma unroll
  for (int j = 0; j < 4; ++j) {
    o[j] = (short)f2bf(lo[j]);
    o[4 + j] = (short)f2bf(hi[j]);
  }
  const int bt = b >> 4, m = b & 15, ks = tid >> 2, q = tid & 3;
  XT[(((size_t)bt * TT + t) * 16 + ks) * 64 + q * 16 + m] = o;
}

// ============================================================================
// Fence-free 64-WG group barrier. Monotonic counters (no reset race):
//   gb[0]        root counter   (8 incs per round)
//   gb[16]       generation     (= completed round)
//   gb[32+s*16]  sub counter s  (8 incs per round)
// All ops relaxed agent-scope -> individually coherent at LLC; no wbl2/inv.
// Ordering: caller does __syncthreads() (vmcnt(0) drain) before arrive().
// ============================================================================
__device__ __forceinline__ void arrive(unsigned* gb, int gm, unsigned round) {
  if (threadIdx.x == 0) {
    unsigned* sub = gb + 32 + ((gm >> 3) << 4);
    unsigned old = __hip_atomic_fetch_add(sub, 1u, __ATOMIC_RELAXED, __HIP_MEMORY_SCOPE_AGENT);
    if (old + 1u == round * 8u) {
      unsigned ro = __hip_atomic_fetch_add(gb, 1u, __ATOMIC_RELAXED, __HIP_MEMORY_SCOPE_AGENT);
      if (ro + 1u == round * 8u) {
        __hip_atomic_store(gb + 16, round, __ATOMIC_RELAXED, __HIP_MEMORY_SCOPE_AGENT);
      }
    }
  }
}

__device__ __forceinline__ void wait_round(unsigned* gb, unsigned round) {
  if (threadIdx.x == 0) {
    while (__hip_atomic_load(gb + 16, __ATOMIC_RELAXED, __HIP_MEMORY_SCOPE_AGENT) < round) {
    }
  }
  __syncthreads();
}

// ============================================================================
// Persistent fused GRU scan. 256 WGs = 4 independent groups (bt) x 64 (ct).
// LDS: wh 96KB + wx 48KB + red 16KB = 160KB exactly -> 1 WG/CU.
// h exchange: bf16 fragment buffer HF in LLC via sc-flagged (atomic) ops only.
// ============================================================================
__global__ __launch_bounds__(256, 1) void gru_main(
    const float* __restrict__ Wxr, const float* __restrict__ bxr,
    const float* __restrict__ Whr,
    const float* __restrict__ Wxz, const float* __restrict__ bxz,
    const float* __restrict__ Whz,
    const float* __restrict__ Wxn, const float* __restrict__ bxn,
    const float* __restrict__ Whn,
    const short8* __restrict__ XT, short* __restrict__ HF,
    unsigned* __restrict__ bar, float* __restrict__ out) {
  extern __shared__ char lds[];
  short8* wh = (short8*)lds;             // [3][32][64]
  short8* wx = (short8*)(lds + 98304);   // [3][16][64]
  float* red = (float*)(lds + 147456);   // [4][4][64][4]

  const int wg = blockIdx.x;
  const int bt = wg >> 6;
  const int ct = wg & 63;
  const int c0 = ct << 4;
  const int tid = threadIdx.x;
  const int wv = tid >> 6;
  const int lane = tid & 63;

  // ---- stage Wh (B-fragment order)
  for (int idx = tid; idx < 3 * 32 * 64; idx += 256) {
    const int g = idx >> 11, rem = idx & 2047, ks = rem >> 6, ln = rem & 63;
    const float* W = (g == 0) ? Whr : (g == 1) ? Whz : Whn;
    const float* src = W + (size_t)(c0 + (ln & 15)) * HD + ks * 32 + (ln >> 4) * 8;
    short8 v;
#pragma unroll
    for (int j = 0; j < 8; ++j) v[j] = (short)f2bf(src[j]);
    wh[idx] = v;
  }
  // ---- stage Wx
  for (int idx = tid; idx < 3 * 16 * 64; idx += 256) {
    const int g = idx >> 10, rem = idx & 1023, ks = rem >> 6, ln = rem & 63;
    const float* W = (g == 0) ? Wxr : (g == 1) ? Wxz : Wxn;
    const float* src = W + (size_t)(c0 + (ln & 15)) * 512 + ks * 32 + (ln >> 4) * 8;
    short8 v;
#pragma unroll
    for (int j = 0; j < 8; ++j) v[j] = (short)f2bf(src[j]);
    wx[idx] = v;
  }
  __syncthreads();

  // ---- per-thread output ownership
  const int c_off = tid & 15, b_off = tid >> 4;
  const int c = c0 + c_off;
  const int b = (bt << 4) + b_off;
  const float br_ = bxr[c], bz_ = bxz[c], bn_ = bxn[c];
  float h_old = 0.f;

  const int hf_elem = (((bt * 32 + (c >> 5)) * 64) + ((c >> 3) & 3) * 16 + b_off) * 8 + (c & 7);
  const int rl = ((b_off >> 2) << 4) + c_off;
  const int rr = b_off & 3;

  unsigned* gb = bar + bt * 256;
  const int gm = wg & 63;

  float* out_hlast = out;
  float* out_hidden = out + BD * HD;

  for (int t = 0; t < TT; ++t) {
    const int p = t & 1;

    // ---- x fragments first (HBM latency hides under barrier wait)
    const short8* xrd = XT + (((size_t)bt * TT + t) * 16 + (wv << 2)) * 64 + lane;
    short8 xa[4];
#pragma unroll
    for (int kk = 0; kk < 4; ++kk) xa[kk] = xrd[kk * 64];

    // ---- wait for h_t (h0 pre-zeroed by memset; parity 0)
    if (t) wait_round(gb, (unsigned)t);

    // ---- h fragments from LLC (device-coherent 8B loads)
    const unsigned long long* hfu = (const unsigned long long*)(HF + p * 65536);
    U16B ha[8];
#pragma unroll
    for (int kk = 0; kk < 8; ++kk) {
      const size_t u = (size_t)(bt * 32 + (wv << 3) + kk) * 64 + lane;
      ha[kk].u[0] = __hip_atomic_load(hfu + u * 2, __ATOMIC_RELAXED, __HIP_MEMORY_SCOPE_AGENT);
      ha[kk].u[1] = __hip_atomic_load(hfu + u * 2 + 1, __ATOMIC_RELAXED, __HIP_MEMORY_SCOPE_AGENT);
    }

    f32x4 aR = {0.f, 0.f, 0.f, 0.f};
    f32x4 aZ = {0.f, 0.f, 0.f, 0.f};
    f32x4 aNh = {0.f, 0.f, 0.f, 0.f};
    f32x4 aNx = {0.f, 0.f, 0.f, 0.f};

    // ---- x MFMAs (ready immediately; overlap h-load flight)
#pragma unroll
    for (int kk = 0; kk < 4; ++kk) {
      const int ks = (wv << 2) + kk;
      aR = __builtin_amdgcn_mfma_f32_16x16x32_bf16(xa[kk], wx[(0 * 16 + ks) * 64 + lane], aR, 0, 0, 0);
      aZ = __builtin_amdgcn_mfma_f32_16x16x32_bf16(xa[kk], wx[(1 * 16 + ks) * 64 + lane], aZ, 0, 0, 0);
      aNx = __builtin_amdgcn_mfma_f32_16x16x32_bf16(xa[kk], wx[(2 * 16 + ks) * 64 + lane], aNx, 0, 0, 0);
    }
    // ---- h MFMAs
#pragma unroll
    for (int kk = 0; kk < 8; ++kk) {
      const int ks = (wv << 3) + kk;
      aR = __builtin_amdgcn_mfma_f32_16x16x32_bf16(ha[kk].s, wh[(0 * 32 + ks) * 64 + lane], aR, 0, 0, 0);
      aZ = __builtin_amdgcn_mfma_f32_16x16x32_bf16(ha[kk].s, wh[(1 * 32 + ks) * 64 + lane], aZ, 0, 0, 0);
      aNh = __builtin_amdgcn_mfma_f32_16x16x32_bf16(ha[kk].s, wh[(2 * 32 + ks) * 64 + lane], aNh, 0, 0, 0);
    }

    // ---- single-round cross-wave K-reduction (16 KB scratch)
    {
      f32x4* r4 = (f32x4*)red;
      r4[(0 * 4 + wv) * 64 + lane] = aR;
      r4[(1 * 4 + wv) * 64 + lane] = aZ;
      r4[(2 * 4 + wv) * 64 + lane] = aNh;
      r4[(3 * 4 + wv) * 64 + lane] = aNx;
    }
    __syncthreads();
    float sR = 0.f, sZ = 0.f, sNh = 0.f, sNx = 0.f;
#pragma unroll
    for (int v = 0; v < 4; ++v) {
      sR += red[((0 * 4 + v) * 64 + rl) * 4 + rr];
      sZ += red[((1 * 4 + v) * 64 + rl) * 4 + rr];
      sNh += red[((2 * 4 + v) * 64 + rl) * 4 + rr];
      sNx += red[((3 * 4 + v) * 64 + rl) * 4 + rr];
    }

    // ---- gates
    const float r = 1.f / (1.f + __expf(-(sR + br_)));
    const float z = 1.f / (1.f + __expf(-(sZ + bz_)));
    float pre_n = sNx + bn_ + r * sNh;
    pre_n = fminf(fmaxf(pre_n, -30.f), 30.f);
    const float e2 = __expf(2.f * pre_n);
    const float n = (e2 - 1.f) / (e2 + 1.f);
    const float hn = (1.f - z) * n + z * h_old;
    h_old = hn;

    out_hidden[((size_t)b * TT + t) * HD + c] = hn;

    if (t < TT - 1) {
      // device-coherent bf16 store of h_{t+1} into parity (t+1)&1
      __hip_atomic_store((unsigned short*)(HF + ((t + 1) & 1) * 65536 + hf_elem),
                         f2bf(hn), __ATOMIC_RELAXED, __HIP_MEMORY_SCOPE_AGENT);
      __syncthreads();  // drains vmcnt(0): HF stores complete at LLC
      arrive(gb, gm, (unsigned)(t + 1));
    } else {
      out_hlast[(size_t)b * HD + c] = hn;
    }
  }
}

// ============================================================================
extern "C" void kernel_launch(void* const* d_in, const int* in_sizes, int n_in,
                              void* d_out, int out_size, void* d_ws, size_t ws_size,
                              hipStream_t stream) {
  const float* inputs = (const float*)d_in[0];
  const float* Wxr = (const float*)d_in[1];
  const float* bxr = (const float*)d_in[2];
  const float* Whr = (const float*)d_in[3];
  const float* Wxz = (const float*)d_in[4];
  const float* bxz = (const float*)d_in[5];
  const float* Whz = (const float*)d_in[6];
  const float* Wxn = (const float*)d_in[7];
  const float* bxn = (const float*)d_in[8];
  const float* Whn = (const float*)d_in[9];
  float* out = (float*)d_out;

  char* ws = (char*)d_ws;
  short8* XT = (short8*)ws;                              // 33,554,432 B
  short* HF = (short*)(ws + 33554432);                   //    262,144 B
  unsigned* bar = (unsigned*)(ws + 33554432 + 262144);   //      4,096 B

  hipMemsetAsync(bar, 0, 4096, stream);
  hipMemsetAsync(HF, 0, 131072, stream);  // h0 = 0 (parity-0 buffer)
  prep_xt<<<dim3(64 * 512), dim3(64), 0, stream>>>(inputs, XT);

  (void)hipFuncSetAttribute((const void*)gru_main,
                            hipFuncAttributeMaxDynamicSharedMemorySize, 163840);
  gru_main<<<dim3(NWG), dim3(256), 163840, stream>>>(
      Wxr, bxr, Whr, Wxz, bxz, Whz, Wxn, bxn, Whn, XT, HF, bar, out);
}

// Round 3
// 1635.818 us; speedup vs baseline: 7.8620x; 1.3242x over previous
//
#include <hip/hip_runtime.h>

typedef __attribute__((ext_vector_type(8))) short short8;
typedef __attribute__((ext_vector_type(4))) float f32x4;

#define TT 512
#define HD 1024
#define BD 64
#define NWG 256

union U16B { short8 s; unsigned long long u[2]; };

// ---- fp32 -> bf16 round-to-nearest-even ----
__device__ __forceinline__ unsigned short f2bf(float f) {
  unsigned u = __float_as_uint(f);
  u += 0x7fffu + ((u >> 16) & 1u);
  return (unsigned short)(u >> 16);
}

// ============================================================================
// Prep: inputs [B][T][512] fp32 -> XT bf16 in MFMA A-fragment order.
// ============================================================================
__global__ void prep_xt(const float* __restrict__ x, short8* __restrict__ XT) {
  const int bid = blockIdx.x;  // b*512 + t
  const int b = bid >> 9;
  const int t = bid & 511;
  const int tid = threadIdx.x;  // k-octet
  const float* src = x + ((size_t)(b * TT + t)) * 512 + tid * 8;
  const f32x4* s4 = (const f32x4*)src;
  f32x4 lo = s4[0], hi = s4[1];
  short8 o;
#pragma unroll
  for (int j = 0; j < 4; ++j) {
    o[j] = (short)f2bf(lo[j]);
    o[4 + j] = (short)f2bf(hi[j]);
  }
  const int bt = b >> 4, m = b & 15, ks = tid >> 2, q = tid & 3;
  XT[(((size_t)bt * TT + t) * 16 + ks) * 64 + q * 16 + m] = o;
}

// ============================================================================
// Persistent fused GRU scan. 256 WGs = 4 independent groups (bt) x 64 (ct).
// bt = blockIdx&3 so each XCD (round-robin blockIdx%8) hosts ONE bt-group ->
// the per-step 16KB x-slice is fetched once per XCD, not 4x.
//
// Sync = flag-vector, no RMWs, no central barrier:
//   flags[bt][wg][wave] (u32) = last step this wave's h slice is visible for.
//   producer wave: h stores (device-scope) -> s_waitcnt vmcnt(0) -> flag store
//   consumer wave: poll all 256 group flags (2x u64 atomic load / lane, __all)
// flag >= t+1 also implies that wave finished READING parity t&1, so the
// 2-deep parity buffer can never be overwritten early (max lead = 1 step).
// LDS: wh 96KB + wx 48KB + red 16KB = 160KB exactly -> 1 WG/CU, grid=256 CUs.
// ============================================================================
__global__ __launch_bounds__(256, 1) void gru_main(
    const float* __restrict__ Wxr, const float* __restrict__ bxr,
    const float* __restrict__ Whr,
    const float* __restrict__ Wxz, const float* __restrict__ bxz,
    const float* __restrict__ Whz,
    const float* __restrict__ Wxn, const float* __restrict__ bxn,
    const float* __restrict__ Whn,
    const short8* __restrict__ XT, short* __restrict__ HF,
    unsigned* __restrict__ bar, float* __restrict__ out) {
  extern __shared__ char lds[];
  short8* wh = (short8*)lds;             // [3][32][64]
  short8* wx = (short8*)(lds + 98304);   // [3][16][64]
  float* red = (float*)(lds + 147456);   // [4][4][64][4]

  const int wg = blockIdx.x;
  const int bt = wg & 3;   // XCD-aligned batch group
  const int ct = wg >> 2;  // 0..63 group member
  const int c0 = ct << 4;
  const int tid = threadIdx.x;
  const int wv = tid >> 6;
  const int lane = tid & 63;

  // ---- stage Wh (B-fragment order)
  for (int idx = tid; idx < 3 * 32 * 64; idx += 256) {
    const int g = idx >> 11, rem = idx & 2047, ks = rem >> 6, ln = rem & 63;
    const float* W = (g == 0) ? Whr : (g == 1) ? Whz : Whn;
    const float* src = W + (size_t)(c0 + (ln & 15)) * HD + ks * 32 + (ln >> 4) * 8;
    short8 v;
#pragma unroll
    for (int j = 0; j < 8; ++j) v[j] = (short)f2bf(src[j]);
    wh[idx] = v;
  }
  // ---- stage Wx
  for (int idx = tid; idx < 3 * 16 * 64; idx += 256) {
    const int g = idx >> 10, rem = idx & 1023, ks = rem >> 6, ln = rem & 63;
    const float* W = (g == 0) ? Wxr : (g == 1) ? Wxz : Wxn;
    const float* src = W + (size_t)(c0 + (ln & 15)) * 512 + ks * 32 + (ln >> 4) * 8;
    short8 v;
#pragma unroll
    for (int j = 0; j < 8; ++j) v[j] = (short)f2bf(src[j]);
    wx[idx] = v;
  }
  __syncthreads();

  // ---- per-thread output ownership
  const int c_off = tid & 15, b_off = tid >> 4;
  const int c = c0 + c_off;
  const int b = (bt << 4) + b_off;
  const float br_ = bxr[c], bz_ = bxz[c], bn_ = bxn[c];
  float h_old = 0.f;

  const int hf_elem = (((bt * 32 + (c >> 5)) * 64) + ((c >> 3) & 3) * 16 + b_off) * 8 + (c & 7);
  const int rl = ((b_off >> 2) << 4) + c_off;
  const int rr = b_off & 3;

  unsigned* flags = bar + bt * 256;                       // [64 wg][4 wave] u32
  const unsigned long long* fl =
      (const unsigned long long*)(flags + lane * 4);      // this lane's wg

  float* out_hlast = out;
  float* out_hidden = out + BD * HD;

  for (int t = 0; t < TT; ++t) {
    const int p = t & 1;

    // ---- x fragments + x MFMAs (independent of h_t; runs before the wait)
    const short8* xrd = XT + (((size_t)bt * TT + t) * 16 + (wv << 2)) * 64 + lane;
    short8 xa[4];
#pragma unroll
    for (int kk = 0; kk < 4; ++kk) xa[kk] = xrd[kk * 64];

    f32x4 aR = {0.f, 0.f, 0.f, 0.f};
    f32x4 aZ = {0.f, 0.f, 0.f, 0.f};
    f32x4 aNh = {0.f, 0.f, 0.f, 0.f};
    f32x4 aNx = {0.f, 0.f, 0.f, 0.f};
#pragma unroll
    for (int kk = 0; kk < 4; ++kk) {
      const int ks = (wv << 2) + kk;
      aR = __builtin_amdgcn_mfma_f32_16x16x32_bf16(xa[kk], wx[(0 * 16 + ks) * 64 + lane], aR, 0, 0, 0);
      aZ = __builtin_amdgcn_mfma_f32_16x16x32_bf16(xa[kk], wx[(1 * 16 + ks) * 64 + lane], aZ, 0, 0, 0);
      aNx = __builtin_amdgcn_mfma_f32_16x16x32_bf16(xa[kk], wx[(2 * 16 + ks) * 64 + lane], aNx, 0, 0, 0);
    }

    // ---- wait for h_t: every wave polls all 256 flags of its group
    if (t) {
      const unsigned tt = (unsigned)t;
      for (;;) {
        unsigned long long a0 = __hip_atomic_load(fl, __ATOMIC_RELAXED, __HIP_MEMORY_SCOPE_AGENT);
        unsigned long long a1 = __hip_atomic_load(fl + 1, __ATOMIC_RELAXED, __HIP_MEMORY_SCOPE_AGENT);
        const unsigned f0 = (unsigned)a0, f1 = (unsigned)(a0 >> 32);
        const unsigned f2 = (unsigned)a1, f3 = (unsigned)(a1 >> 32);
        const int ok = (f0 >= tt) & (f1 >= tt) & (f2 >= tt) & (f3 >= tt);
        if (__all(ok)) break;
      }
    }

    // ---- h fragments from LLC (device-coherent 8B loads) + h MFMAs
    const unsigned long long* hfu = (const unsigned long long*)(HF + p * 65536);
    U16B ha[8];
#pragma unroll
    for (int kk = 0; kk < 8; ++kk) {
      const size_t u = (size_t)(bt * 32 + (wv << 3) + kk) * 64 + lane;
      ha[kk].u[0] = __hip_atomic_load(hfu + u * 2, __ATOMIC_RELAXED, __HIP_MEMORY_SCOPE_AGENT);
      ha[kk].u[1] = __hip_atomic_load(hfu + u * 2 + 1, __ATOMIC_RELAXED, __HIP_MEMORY_SCOPE_AGENT);
    }
#pragma unroll
    for (int kk = 0; kk < 8; ++kk) {
      const int ks = (wv << 3) + kk;
      aR = __builtin_amdgcn_mfma_f32_16x16x32_bf16(ha[kk].s, wh[(0 * 32 + ks) * 64 + lane], aR, 0, 0, 0);
      aZ = __builtin_amdgcn_mfma_f32_16x16x32_bf16(ha[kk].s, wh[(1 * 32 + ks) * 64 + lane], aZ, 0, 0, 0);
      aNh = __builtin_amdgcn_mfma_f32_16x16x32_bf16(ha[kk].s, wh[(2 * 32 + ks) * 64 + lane], aNh, 0, 0, 0);
    }

    // ---- single-round cross-wave K-reduction
    {
      f32x4* r4 = (f32x4*)red;
      r4[(0 * 4 + wv) * 64 + lane] = aR;
      r4[(1 * 4 + wv) * 64 + lane] = aZ;
      r4[(2 * 4 + wv) * 64 + lane] = aNh;
      r4[(3 * 4 + wv) * 64 + lane] = aNx;
    }
    __syncthreads();
    float sR = 0.f, sZ = 0.f, sNh = 0.f, sNx = 0.f;
#pragma unroll
    for (int v = 0; v < 4; ++v) {
      sR += red[((0 * 4 + v) * 64 + rl) * 4 + rr];
      sZ += red[((1 * 4 + v) * 64 + rl) * 4 + rr];
      sNh += red[((2 * 4 + v) * 64 + rl) * 4 + rr];
      sNx += red[((3 * 4 + v) * 64 + rl) * 4 + rr];
    }

    // ---- gates
    const float r = 1.f / (1.f + __expf(-(sR + br_)));
    const float z = 1.f / (1.f + __expf(-(sZ + bz_)));
    float pre_n = sNx + bn_ + r * sNh;
    pre_n = fminf(fmaxf(pre_n, -30.f), 30.f);
    const float e2 = __expf(2.f * pre_n);
    const float n = (e2 - 1.f) / (e2 + 1.f);
    const float hn = (1.f - z) * n + z * h_old;
    h_old = hn;

    if (t < TT - 1) {
      // h_{t+1} -> parity (t+1)&1, device-coherent; then ack, then flag
      __hip_atomic_store((unsigned short*)(HF + ((t + 1) & 1) * 65536 + hf_elem),
                         f2bf(hn), __ATOMIC_RELAXED, __HIP_MEMORY_SCOPE_AGENT);
      asm volatile("s_waitcnt vmcnt(0)" ::: "memory");  // this wave's h acked at LLC
      if (lane == 0) {
        __hip_atomic_store(flags + ct * 4 + wv, (unsigned)(t + 1),
                           __ATOMIC_RELAXED, __HIP_MEMORY_SCOPE_AGENT);
      }
      // out store drains under the next poll (off the critical path)
      out_hidden[((size_t)b * TT + t) * HD + c] = hn;
    } else {
      out_hidden[((size_t)b * TT + t) * HD + c] = hn;
      out_hlast[(size_t)b * HD + c] = hn;
    }
  }
}

// ============================================================================
extern "C" void kernel_launch(void* const* d_in, const int* in_sizes, int n_in,
                              void* d_out, int out_size, void* d_ws, size_t ws_size,
                              hipStream_t stream) {
  const float* inputs = (const float*)d_in[0];
  const float* Wxr = (const float*)d_in[1];
  const float* bxr = (const float*)d_in[2];
  const float* Whr = (const float*)d_in[3];
  const float* Wxz = (const float*)d_in[4];
  const float* bxz = (const float*)d_in[5];
  const float* Whz = (const float*)d_in[6];
  const float* Wxn = (const float*)d_in[7];
  const float* bxn = (const float*)d_in[8];
  const float* Whn = (const float*)d_in[9];
  float* out = (float*)d_out;

  char* ws = (char*)d_ws;
  short8* XT = (short8*)ws;                              // 33,554,432 B
  short* HF = (short*)(ws + 33554432);                   //    262,144 B
  unsigned* bar = (unsigned*)(ws + 33554432 + 262144);   //      4,096 B (flags)

  hipMemsetAsync(bar, 0, 4096, stream);
  hipMemsetAsync(HF, 0, 131072, stream);  // h0 = 0 (parity-0 buffer)
  prep_xt<<<dim3(64 * 512), dim3(64), 0, stream>>>(inputs, XT);

  (void)hipFuncSetAttribute((const void*)gru_main,
                            hipFuncAttributeMaxDynamicSharedMemorySize, 163840);
  gru_main<<<dim3(NWG), dim3(256), 163840, stream>>>(
      Wxr, bxr, Whr, Wxz, bxz, Whz, Wxn, bxn, Whn, XT, HF, bar, out);
}